// Round 4
// baseline (382.719 us; speedup 1.0000x reference)
//
#include <hip/hip_runtime.h>
#include <hip/hip_bf16.h>
#include <cstdint>

#define D  128    // feature dim / MLP hidden dim
#define NT 256    // combined table row: cols 0-127 = A-part, 128-255 = B-part

typedef __attribute__((ext_vector_type(8))) short bf16x8;
typedef __attribute__((ext_vector_type(4))) float f32x4;

// pack two fp32 -> two bf16 (round-half-up): 2 adds + 1 v_perm
__device__ __forceinline__ unsigned int packbf(float lo, float hi) {
    const unsigned int ulo = __float_as_uint(lo) + 0x8000u;
    const unsigned int uhi = __float_as_uint(hi) + 0x8000u;
    return __builtin_amdgcn_perm(uhi, ulo, 0x07060302);  // hi16(uhi)<<16 | hi16(ulo)
}

// ---------------------------------------------------------------------------
// Pack W1cat (256x128 fp32, rows 0-127 -> A-part, 128-255 -> B-part) into
// bf16 MFMA-fragment-linear layout: frag (cg,ks) for lane(lr,lg) at
// Wp[((cg*4+ks)*64 + lane)*8 ..], elem i = W1[(half*128 + ks*32 + lg*8 + i)*128
// + (cg&7)*16 + lr], half = cg>>3.  Total 64 KB.
// ---------------------------------------------------------------------------
__global__ __launch_bounds__(256) void pack_w1(
    const float* __restrict__ W1, unsigned short* __restrict__ Wp)
{
    const int t = blockIdx.x * 256 + threadIdx.x;   // 0..4095
    if (t >= 4096) return;
    const int lane = t & 63;
    const int fc = t >> 6;          // cg*4+ks
    const int cg = fc >> 2, ks = fc & 3;
    const int lr = lane & 15, lg = lane >> 4;
    const int half = cg >> 3;
    const int col = (cg & 7) * 16 + lr;
    const int krow = half * 128 + ks * 32 + lg * 8;
    const float* wp = W1 + (size_t)krow * D + col;
    uint4 u;
    u.x = packbf(wp[0 * D], wp[1 * D]);
    u.y = packbf(wp[2 * D], wp[3 * D]);
    u.z = packbf(wp[4 * D], wp[5 * D]);
    u.w = packbf(wp[6 * D], wp[7 * D]);
    reinterpret_cast<uint4*>(Wp)[t] = u;
}

// ---------------------------------------------------------------------------
// Node projection via MFMA, W1 fragments staged in LDS (64 KB / block).
// 8 waves/block; each wave owns 16-node chunks (grid-strided), all 256 cols.
// x frags (B-operand) loaded straight from global; frags re-read from LDS
// per chunk with conflict-free ds_read_b128.
// ---------------------------------------------------------------------------
__global__ __launch_bounds__(512, 4) void node_mlp_mfma(
    const float* __restrict__ x, const unsigned short* __restrict__ Wp,
    unsigned short* __restrict__ T, int N)
{
    __shared__ uint4 ldsW[4096];    // 64 KB

    // stage packed W1 frags: 512 threads x 8 x 16B, coalesced
    {
        const uint4* s = reinterpret_cast<const uint4*>(Wp);
        #pragma unroll
        for (int i = 0; i < 8; ++i)
            ldsW[threadIdx.x + i * 512] = s[threadIdx.x + i * 512];
    }
    __syncthreads();

    const int lane = threadIdx.x & 63;
    const int wib  = threadIdx.x >> 6;            // wave in block
    const int wid  = blockIdx.x * 8 + wib;
    const int nW   = gridDim.x * 8;
    const int lr = lane & 15, lg = lane >> 4;
    const int NCH = (N + 15) >> 4;

    const uint4* fragBase = ldsW + lane;          // frag (cg,ks) at fragBase[(cg*4+ks)*64]

    for (int c = wid; c < NCH; c += nW) {
        int row = c * 16 + lr;
        if (row >= N) row = N - 1;
        const float4* pf = reinterpret_cast<const float4*>(x + (size_t)row * D + 8 * lg);
        const float4 r0 = pf[0],  r1 = pf[1],  r2 = pf[8],  r3 = pf[9];
        const float4 r4 = pf[16], r5 = pf[17], r6 = pf[24], r7 = pf[25];

        bf16x8 xf[4];
        {
            uint4 u;
            u.x = packbf(r0.x, r0.y); u.y = packbf(r0.z, r0.w);
            u.z = packbf(r1.x, r1.y); u.w = packbf(r1.z, r1.w);
            xf[0] = __builtin_bit_cast(bf16x8, u);
            u.x = packbf(r2.x, r2.y); u.y = packbf(r2.z, r2.w);
            u.z = packbf(r3.x, r3.y); u.w = packbf(r3.z, r3.w);
            xf[1] = __builtin_bit_cast(bf16x8, u);
            u.x = packbf(r4.x, r4.y); u.y = packbf(r4.z, r4.w);
            u.z = packbf(r5.x, r5.y); u.w = packbf(r5.z, r5.w);
            xf[2] = __builtin_bit_cast(bf16x8, u);
            u.x = packbf(r6.x, r6.y); u.y = packbf(r6.z, r6.w);
            u.z = packbf(r7.x, r7.y); u.w = packbf(r7.z, r7.w);
            xf[3] = __builtin_bit_cast(bf16x8, u);
        }

        f32x4 acc[16];
        #pragma unroll
        for (int cg = 0; cg < 16; ++cg) acc[cg] = (f32x4){0.f, 0.f, 0.f, 0.f};

        #pragma unroll
        for (int ks = 0; ks < 4; ++ks) {
            #pragma unroll
            for (int cg = 0; cg < 16; ++cg) {
                const bf16x8 wf = __builtin_bit_cast(bf16x8, fragBase[(cg * 4 + ks) * 64]);
                acc[cg] = __builtin_amdgcn_mfma_f32_16x16x32_bf16(wf, xf[ks], acc[cg], 0, 0, 0);
            }
        }

        const int node = c * 16 + lr;
        if (node < N) {
            unsigned short* orow = T + (size_t)node * NT + lg * 4;
            #pragma unroll
            for (int cg = 0; cg < 16; ++cg) {
                uint2 o;
                o.x = packbf(acc[cg][0], acc[cg][1]);
                o.y = packbf(acc[cg][2], acc[cg][3]);
                *reinterpret_cast<uint2*>(orow + cg * 16) = o;
            }
        }
    }
}

// ---------------------------------------------------------------------------
// Edge kernel: 8 lanes/edge; persistent grid-stride waves, b1/W2/b2 hoisted,
// 2-deep software pipeline of the table gathers; tail fused on lane sub==0.
// ---------------------------------------------------------------------------
__device__ __forceinline__ float acc_pair(uint32_t wa, uint32_t wb,
                                          float blo, float bhi,
                                          float w2lo, float w2hi, float p) {
    const float alo = __uint_as_float(wa << 16);
    const float ahi = __uint_as_float(wa & 0xffff0000u);
    const float clo = __uint_as_float(wb << 16);
    const float chi = __uint_as_float(wb & 0xffff0000u);
    const float h0 = fmaxf(alo + clo + blo, 0.f);
    const float h1 = fmaxf(ahi + chi + bhi, 0.f);
    p = fmaf(h0, w2lo, p);
    p = fmaf(h1, w2hi, p);
    return p;
}

__global__ __launch_bounds__(256) void edge_kernel(
    const unsigned short* __restrict__ T,
    const int* __restrict__ src, const int* __restrict__ dst,
    const float* __restrict__ b1, const float* __restrict__ W2,
    const float* __restrict__ b2,
    const float* __restrict__ u_gate, const float* __restrict__ u_bern,
    float* __restrict__ out, int E)
{
    const int sub = threadIdx.x & 7;
    const int g0 = (blockIdx.x * blockDim.x + threadIdx.x) >> 3;
    const int gstride = (gridDim.x * blockDim.x) >> 3;

    // hoisted per-lane constants (dims sub*16 .. sub*16+15)
    const float4* Bv = reinterpret_cast<const float4*>(b1 + sub * 16);
    const float4* Wv = reinterpret_cast<const float4*>(W2 + sub * 16);
    const float4 bb0 = Bv[0], bb1 = Bv[1], bb2 = Bv[2], bb3 = Bv[3];
    const float4 w0 = Wv[0], w1 = Wv[1], w2 = Wv[2], w3 = Wv[3];
    const float b2v = b2[0];

    int e = g0;
    if (e >= E) return;

    // prologue loads for first edge
    int s = src[e], d = dst[e];
    const uint4* Ap = reinterpret_cast<const uint4*>(T + (size_t)s * NT + sub * 16);
    const uint4* Bp = reinterpret_cast<const uint4*>(T + (size_t)d * NT + 128 + sub * 16);
    uint4 a0 = Ap[0], a1 = Ap[1];
    uint4 c0 = Bp[0], c1 = Bp[1];

    for (;;) {
        const int en = e + gstride;
        const bool more = en < E;
        uint4 na0, na1, nc0, nc1;
        if (more) {
            const int sn = src[en], dn = dst[en];
            const uint4* An = reinterpret_cast<const uint4*>(T + (size_t)sn * NT + sub * 16);
            const uint4* Bn = reinterpret_cast<const uint4*>(T + (size_t)dn * NT + 128 + sub * 16);
            na0 = An[0]; na1 = An[1];
            nc0 = Bn[0]; nc1 = Bn[1];
        }

        float p = 0.f;
        p = acc_pair(a0.x, c0.x, bb0.x, bb0.y, w0.x, w0.y, p);
        p = acc_pair(a0.y, c0.y, bb0.z, bb0.w, w0.z, w0.w, p);
        p = acc_pair(a0.z, c0.z, bb1.x, bb1.y, w1.x, w1.y, p);
        p = acc_pair(a0.w, c0.w, bb1.z, bb1.w, w1.z, w1.w, p);
        p = acc_pair(a1.x, c1.x, bb2.x, bb2.y, w2.x, w2.y, p);
        p = acc_pair(a1.y, c1.y, bb2.z, bb2.w, w2.z, w2.w, p);
        p = acc_pair(a1.z, c1.z, bb3.x, bb3.y, w3.x, w3.y, p);
        p = acc_pair(a1.w, c1.w, bb3.z, bb3.w, w3.z, w3.w, p);

        p += __shfl_xor(p, 1, 64);
        p += __shfl_xor(p, 2, 64);
        p += __shfl_xor(p, 4, 64);

        if (sub == 0) {
            const float logit = p + b2v;
            // gumbel-sigmoid gate
            const float ug  = u_gate[e];
            const float eps = fmaf(-0.9998f, ug, 0.9999f);     // (BIAS-(1-BIAS))*u + (1-BIAS)
            const float g   = logf(eps) - log1pf(-eps) + logit; // TEMP_GATE = 1
            const float ew  = 1.f / (1.f + expf(-g));
            // RelaxedBernoulli(temp=0.9).rsample
            const float att = fminf(fmaxf(ew, 0.01f), 0.99f);
            const float bl  = logf(att) - log1pf(-att);
            const float ub  = fminf(fmaxf(u_bern[e], 1e-7f), 1.f - 1e-7f);
            const float arg = (bl + logf(ub) - log1pf(-ub)) * (1.0f / 0.9f);
            const float wv  = 1.f / (1.f + expf(-arg));
            out[e] = wv;   // mask=(w>0) is identity for sigmoid output
        }

        if (!more) break;
        a0 = na0; a1 = na1; c0 = nc0; c1 = nc1;
        e = en;
    }
}

extern "C" void kernel_launch(void* const* d_in, const int* in_sizes, int n_in,
                              void* d_out, int out_size, void* d_ws, size_t ws_size,
                              hipStream_t stream)
{
    const float* node_emb = (const float*)d_in[0];
    const int*   src      = (const int*)d_in[1];
    const int*   dst      = (const int*)d_in[2];
    const float* W1       = (const float*)d_in[3];
    const float* b1       = (const float*)d_in[4];
    const float* W2       = (const float*)d_in[5];
    const float* b2       = (const float*)d_in[6];
    const float* u_gate   = (const float*)d_in[7];
    const float* u_bern   = (const float*)d_in[8];
    float* out = (float*)d_out;

    const int N = in_sizes[0] / D;
    const int E = in_sizes[1];

    unsigned short* Wp = (unsigned short*)d_ws;            // 64 KB packed W1 frags
    unsigned short* T  = Wp + 32768;                       // [N][256] bf16

    pack_w1<<<16, 256, 0, stream>>>(W1, Wp);
    node_mlp_mfma<<<512, 512, 0, stream>>>(node_emb, Wp, T, N);
    edge_kernel<<<1024, 256, 0, stream>>>(T, src, dst, b1, W2, b2,
                                          u_gate, u_bern, out, E);
}

// Round 5
// 202.694 us; speedup vs baseline: 1.8882x; 1.8882x over previous
//
#include <hip/hip_runtime.h>
#include <hip/hip_bf16.h>
#include <cstdint>

#define D  128    // feature dim / MLP hidden dim
#define NT 256    // combined table row: cols 0-127 = A-part, 128-255 = B-part
#define LSTRIDE 544   // LDS transpose-tile row stride in bytes (512 + 32 pad)

typedef __attribute__((ext_vector_type(8))) short bf16x8;
typedef __attribute__((ext_vector_type(4))) float f32x4;

// pack two fp32 -> two bf16 (round-half-up): 2 adds + 1 v_perm
__device__ __forceinline__ unsigned int packbf(float lo, float hi) {
    const unsigned int ulo = __float_as_uint(lo) + 0x8000u;
    const unsigned int uhi = __float_as_uint(hi) + 0x8000u;
    return __builtin_amdgcn_perm(uhi, ulo, 0x07060302);  // hi16(uhi)<<16 | hi16(ulo)
}

// ---------------------------------------------------------------------------
// Pack W1cat (rows 0-127 -> A-part, 128-255 -> B-part) into bf16
// MFMA-fragment-linear layout: frag (cg,ks), lane l, at uint4 index
// (cg*4+ks)*64 + l;  elem i = W1[(half*128 + ks*32 + lg*8 + i)*128 +
// (cg&7)*16 + lr], half = cg>>3.  Total 64 KB.  (verified R3/R4)
// ---------------------------------------------------------------------------
__global__ __launch_bounds__(256) void pack_w1(
    const float* __restrict__ W1, unsigned short* __restrict__ Wp)
{
    const int t = blockIdx.x * 256 + threadIdx.x;   // 0..4095
    if (t >= 4096) return;
    const int lane = t & 63;
    const int fc = t >> 6;          // cg*4+ks
    const int cg = fc >> 2, ks = fc & 3;
    const int lr = lane & 15, lg = lane >> 4;
    const int half = cg >> 3;
    const int col = (cg & 7) * 16 + lr;
    const int krow = half * 128 + ks * 32 + lg * 8;
    const float* wp = W1 + (size_t)krow * D + col;
    uint4 u;
    u.x = packbf(wp[0 * D], wp[1 * D]);
    u.y = packbf(wp[2 * D], wp[3 * D]);
    u.z = packbf(wp[4 * D], wp[5 * D]);
    u.w = packbf(wp[6 * D], wp[7 * D]);
    reinterpret_cast<uint4*>(Wp)[t] = u;
}

// ---------------------------------------------------------------------------
// Node projection via MFMA. One block = one 64-node macro-chunk. 4 waves;
// wave w owns col-groups cg = 4w..4w+3 (jj 64w..64w+63), W frags in VGPRs
// (loaded once from packed Wp, L2-resident). Results transposed through a
// 64x544B LDS tile, then dumped with full-line coalesced uint4 stores.
// ---------------------------------------------------------------------------
__global__ __launch_bounds__(256, 3) void node_mlp_mfma(
    const float* __restrict__ x, const unsigned short* __restrict__ Wp,
    unsigned short* __restrict__ T, int N)
{
    __shared__ unsigned char lbuf[64 * LSTRIDE];   // 34 KB

    const int t = threadIdx.x;
    const int lane = t & 63;
    const int w = t >> 6;               // wave in block: owns jj [64w, 64w+64)
    const int lr = lane & 15;           // node-within-subchunk
    const int lg = lane >> 4;           // k-subgroup / jj quad selector
    const int base = blockIdx.x * 64;   // first node of this macro-chunk

    // ---- W fragments (16 per wave = 64 VGPR), coalesced from packed Wp
    bf16x8 wf[4][4];
    {
        const uint4* wsrc = reinterpret_cast<const uint4*>(Wp);
        #pragma unroll
        for (int c = 0; c < 4; ++c)
            #pragma unroll
            for (int ks = 0; ks < 4; ++ks)
                wf[c][ks] = __builtin_bit_cast(bf16x8,
                    wsrc[(((w * 4 + c) * 4 + ks) << 6) + lane]);
    }

    // ---- 4 sub-chunks of 16 nodes
    #pragma unroll
    for (int s = 0; s < 4; ++s) {
        int row = base + s * 16 + lr;
        if (row > N - 1) row = N - 1;
        const float4* pf = reinterpret_cast<const float4*>(x + (size_t)row * D + 8 * lg);
        const float4 r0 = pf[0],  r1 = pf[1],  r2 = pf[8],  r3 = pf[9];
        const float4 r4 = pf[16], r5 = pf[17], r6 = pf[24], r7 = pf[25];

        bf16x8 xf[4];
        {
            uint4 u;
            u.x = packbf(r0.x, r0.y); u.y = packbf(r0.z, r0.w);
            u.z = packbf(r1.x, r1.y); u.w = packbf(r1.z, r1.w);
            xf[0] = __builtin_bit_cast(bf16x8, u);
            u.x = packbf(r2.x, r2.y); u.y = packbf(r2.z, r2.w);
            u.z = packbf(r3.x, r3.y); u.w = packbf(r3.z, r3.w);
            xf[1] = __builtin_bit_cast(bf16x8, u);
            u.x = packbf(r4.x, r4.y); u.y = packbf(r4.z, r4.w);
            u.z = packbf(r5.x, r5.y); u.w = packbf(r5.z, r5.w);
            xf[2] = __builtin_bit_cast(bf16x8, u);
            u.x = packbf(r6.x, r6.y); u.y = packbf(r6.z, r6.w);
            u.z = packbf(r7.x, r7.y); u.w = packbf(r7.z, r7.w);
            xf[3] = __builtin_bit_cast(bf16x8, u);
        }

        f32x4 acc[4];
        #pragma unroll
        for (int c = 0; c < 4; ++c) acc[c] = (f32x4){0.f, 0.f, 0.f, 0.f};
        #pragma unroll
        for (int ks = 0; ks < 4; ++ks)
            #pragma unroll
            for (int c = 0; c < 4; ++c)
                acc[c] = __builtin_amdgcn_mfma_f32_16x16x32_bf16(
                    wf[c][ks], xf[ks], acc[c], 0, 0, 0);

        // lane holds node = s*16+lr, jj = w*64 + c*16 + lg*4 + r  ->  LDS tile
        unsigned char* p = lbuf + (s * 16 + lr) * LSTRIDE + w * 128 + lg * 8;
        #pragma unroll
        for (int c = 0; c < 4; ++c) {
            uint2 o;
            o.x = packbf(acc[c][0], acc[c][1]);
            o.y = packbf(acc[c][2], acc[c][3]);
            *reinterpret_cast<uint2*>(p + c * 32) = o;
        }
    }

    __syncthreads();

    // ---- coalesced dump: thread t -> row t>>2, 16B chunk (t&3); 8 iters of
    // 64B-contiguous-per-row full-line stores
    {
        const int drow = t >> 2;
        const int dcol = (t & 3) * 16;            // byte offset in row
        const int node = base + drow;
        if (node < N) {
            const unsigned char* sp = lbuf + drow * LSTRIDE + dcol;
            unsigned char* gp = reinterpret_cast<unsigned char*>(T) +
                                (size_t)node * (NT * 2) + dcol;
            #pragma unroll
            for (int i = 0; i < 8; ++i)
                *reinterpret_cast<uint4*>(gp + i * 64) =
                    *reinterpret_cast<const uint4*>(sp + i * 64);
        }
    }
}

// ---------------------------------------------------------------------------
// Edge kernel (R3 verbatim, measured 82 us): 8 lanes/edge; b1 re-added here;
// gumbel/bernoulli tail fused on lane sub==0.
// ---------------------------------------------------------------------------
__device__ __forceinline__ float acc_pair(uint32_t wa, uint32_t wb,
                                          float blo, float bhi,
                                          float w2lo, float w2hi, float p) {
    const float alo = __uint_as_float(wa << 16);
    const float ahi = __uint_as_float(wa & 0xffff0000u);
    const float clo = __uint_as_float(wb << 16);
    const float chi = __uint_as_float(wb & 0xffff0000u);
    const float h0 = fmaxf(alo + clo + blo, 0.f);
    const float h1 = fmaxf(ahi + chi + bhi, 0.f);
    p = fmaf(h0, w2lo, p);
    p = fmaf(h1, w2hi, p);
    return p;
}

__global__ __launch_bounds__(256) void edge_kernel(
    const unsigned short* __restrict__ T,
    const int* __restrict__ src, const int* __restrict__ dst,
    const float* __restrict__ b1, const float* __restrict__ W2,
    const float* __restrict__ b2,
    const float* __restrict__ u_gate, const float* __restrict__ u_bern,
    float* __restrict__ out, int E)
{
    const int gid = blockIdx.x * blockDim.x + threadIdx.x;
    const int e = gid >> 3;
    if (e >= E) return;
    const int sub = threadIdx.x & 7;

    const int s = src[e];
    const int d = dst[e];

    const uint4* Ap = reinterpret_cast<const uint4*>(T + (size_t)s * NT + sub * 16);
    const uint4* Bp = reinterpret_cast<const uint4*>(T + (size_t)d * NT + 128 + sub * 16);
    const float4* Bv = reinterpret_cast<const float4*>(b1 + sub * 16);
    const float4* Wv = reinterpret_cast<const float4*>(W2 + sub * 16);

    const uint4 a0 = Ap[0], a1 = Ap[1];
    const uint4 c0 = Bp[0], c1 = Bp[1];
    const float4 bb0 = Bv[0], bb1 = Bv[1], bb2 = Bv[2], bb3 = Bv[3];
    const float4 w0 = Wv[0], w1 = Wv[1], w2 = Wv[2], w3 = Wv[3];

    float p = 0.f;
    p = acc_pair(a0.x, c0.x, bb0.x, bb0.y, w0.x, w0.y, p);
    p = acc_pair(a0.y, c0.y, bb0.z, bb0.w, w0.z, w0.w, p);
    p = acc_pair(a0.z, c0.z, bb1.x, bb1.y, w1.x, w1.y, p);
    p = acc_pair(a0.w, c0.w, bb1.z, bb1.w, w1.z, w1.w, p);
    p = acc_pair(a1.x, c1.x, bb2.x, bb2.y, w2.x, w2.y, p);
    p = acc_pair(a1.y, c1.y, bb2.z, bb2.w, w2.z, w2.w, p);
    p = acc_pair(a1.z, c1.z, bb3.x, bb3.y, w3.x, w3.y, p);
    p = acc_pair(a1.w, c1.w, bb3.z, bb3.w, w3.z, w3.w, p);

    p += __shfl_xor(p, 1, 64);
    p += __shfl_xor(p, 2, 64);
    p += __shfl_xor(p, 4, 64);

    if (sub == 0) {
        const float logit = p + b2[0];
        // gumbel-sigmoid gate
        const float ug  = u_gate[e];
        const float eps = fmaf(-0.9998f, ug, 0.9999f);        // (BIAS-(1-BIAS))*u + (1-BIAS)
        const float g   = logf(eps) - log1pf(-eps) + logit;    // TEMP_GATE = 1
        const float ew  = 1.f / (1.f + expf(-g));              // edge_weight
        // RelaxedBernoulli(temp=0.9).rsample
        const float att = fminf(fmaxf(ew, 0.01f), 0.99f);
        const float bl  = logf(att) - log1pf(-att);
        const float ub  = fminf(fmaxf(u_bern[e], 1e-7f), 1.f - 1e-7f);
        const float arg = (bl + logf(ub) - log1pf(-ub)) * (1.0f / 0.9f);
        const float wv  = 1.f / (1.f + expf(-arg));
        out[e] = wv;   // mask=(w>0) is identity for sigmoid output
    }
}

extern "C" void kernel_launch(void* const* d_in, const int* in_sizes, int n_in,
                              void* d_out, int out_size, void* d_ws, size_t ws_size,
                              hipStream_t stream)
{
    const float* node_emb = (const float*)d_in[0];
    const int*   src      = (const int*)d_in[1];
    const int*   dst      = (const int*)d_in[2];
    const float* W1       = (const float*)d_in[3];
    const float* b1       = (const float*)d_in[4];
    const float* W2       = (const float*)d_in[5];
    const float* b2       = (const float*)d_in[6];
    const float* u_gate   = (const float*)d_in[7];
    const float* u_bern   = (const float*)d_in[8];
    float* out = (float*)d_out;

    const int N = in_sizes[0] / D;
    const int E = in_sizes[1];

    unsigned short* Wp = (unsigned short*)d_ws;            // 64 KB packed W1 frags
    unsigned short* T  = Wp + 32768;                       // [N][256] bf16

    pack_w1<<<16, 256, 0, stream>>>(W1, Wp);

    const int nMacro = (N + 63) / 64;                      // one 64-node macro per block
    node_mlp_mfma<<<nMacro, 256, 0, stream>>>(node_emb, Wp, T, N);

    const long long dotThreads = (long long)E * 8;
    const int blocksE = (int)((dotThreads + 255) / 256);
    edge_kernel<<<blocksE, 256, 0, stream>>>(T, src, dst, b1, W2, b2,
                                             u_gate, u_bern, out, E);
}

// Round 6
// 174.610 us; speedup vs baseline: 2.1918x; 1.1608x over previous
//
#include <hip/hip_runtime.h>
#include <hip/hip_bf16.h>
#include <cstdint>

#define D  128        // feature dim / MLP hidden dim
#define NT 256        // combined table row: cols 0-127 = A-part, 128-255 = B-part
#define OSTRIDE 544   // output transpose-tile row stride in bytes (512 + 32 pad)

typedef __attribute__((ext_vector_type(8))) short bf16x8;
typedef __attribute__((ext_vector_type(4))) float f32x4;

__device__ __forceinline__ unsigned int packbf(float lo, float hi) {
    const unsigned int ulo = __float_as_uint(lo) + 0x8000u;
    const unsigned int uhi = __float_as_uint(hi) + 0x8000u;
    return __builtin_amdgcn_perm(uhi, ulo, 0x07060302);  // hi16(uhi)<<16 | hi16(ulo)
}

// ---------------------------------------------------------------------------
// Pack W1cat into bf16 MFMA-fragment-linear layout (verified R3-R5).
// frag (cg,ks), lane l at uint4 index (cg*4+ks)*64 + l; elem i =
// W1[(half*128 + ks*32 + lg*8 + i)*128 + (cg&7)*16 + lr], half = cg>>3.
// ---------------------------------------------------------------------------
__global__ __launch_bounds__(256) void pack_w1(
    const float* __restrict__ W1, unsigned short* __restrict__ Wp)
{
    const int t = blockIdx.x * 256 + threadIdx.x;   // 0..4095
    if (t >= 4096) return;
    const int lane = t & 63;
    const int fc = t >> 6;
    const int cg = fc >> 2, ks = fc & 3;
    const int lr = lane & 15, lg = lane >> 4;
    const int half = cg >> 3;
    const int col = (cg & 7) * 16 + lr;
    const int krow = half * 128 + ks * 32 + lg * 8;
    const float* wp = W1 + (size_t)krow * D + col;
    uint4 u;
    u.x = packbf(wp[0 * D], wp[1 * D]);
    u.y = packbf(wp[2 * D], wp[3 * D]);
    u.z = packbf(wp[4 * D], wp[5 * D]);
    u.w = packbf(wp[6 * D], wp[7 * D]);
    reinterpret_cast<uint4*>(Wp)[t] = u;
}

// ---------------------------------------------------------------------------
// Node projection. One block = 64 nodes. Phase 1: stage x ONCE, coalesced,
// packed to bf16 fragment-linear LDS (XOR-swizzled). Phase 2: 4 waves x
// 4 subchunks of MFMA (W frags in VGPRs), results into obuf transpose tile.
// Phase 3: full-line coalesced dump.
// ---------------------------------------------------------------------------
__global__ __launch_bounds__(256, 3) void node_mlp_mfma(
    const float* __restrict__ x, const unsigned short* __restrict__ Wp,
    unsigned short* __restrict__ T, int N)
{
    __shared__ unsigned char obuf[64 * OSTRIDE];   // 34816 B
    __shared__ uint4 xfrag[1024];                  // 16384 B (bf16 frags)

    const int t = threadIdx.x;
    const int lane = t & 63;
    const int w = t >> 6;               // wave: owns jj [64w, 64w+64)
    const int lr = lane & 15;
    const int lg = lane >> 4;
    const int base = blockIdx.x * 64;

    // ---- W fragments (16 per wave = 64 VGPR), coalesced from packed Wp
    bf16x8 wf[4][4];
    {
        const uint4* wsrc = reinterpret_cast<const uint4*>(Wp);
        #pragma unroll
        for (int c = 0; c < 4; ++c)
            #pragma unroll
            for (int ks = 0; ks < 4; ++ks)
                wf[c][ks] = __builtin_bit_cast(bf16x8,
                    wsrc[(((w * 4 + c) * 4 + ks) << 6) + lane]);
    }

    // ---- Phase 1: stage x tile (64 rows x 512 B) as bf16 fragments.
    // Chunk m (32 B): row r = m>>4, col8 c8 = m&15. Consecutive t ->
    // contiguous global addresses (fully coalesced).
    #pragma unroll
    for (int i = 0; i < 4; ++i) {
        const int m = t + 256 * i;
        const int r = m >> 4;
        const int c8 = m & 15;
        int row = base + r; if (row > N - 1) row = N - 1;
        const float4* px = reinterpret_cast<const float4*>(x + (size_t)row * D + c8 * 8);
        const float4 v0 = px[0], v1 = px[1];
        uint4 u;
        u.x = packbf(v0.x, v0.y); u.y = packbf(v0.z, v0.w);
        u.z = packbf(v1.x, v1.y); u.w = packbf(v1.z, v1.w);
        const int s = r >> 4, lr2 = r & 15, ks = c8 >> 2, lg2 = c8 & 3;
        int idx = ((s * 4 + ks) << 6) + (lg2 << 4) + lr2;
        idx ^= ((idx >> 4) & 3) << 2;       // XOR swizzle (bank spread)
        xfrag[idx] = u;
    }
    __syncthreads();

    // ---- Phase 2: MFMA per subchunk; frag reads lane-linear (+ same XOR)
    const int lxor = lane ^ (((lane >> 4) & 3) << 2);
    #pragma unroll
    for (int s = 0; s < 4; ++s) {
        bf16x8 xf[4];
        #pragma unroll
        for (int ks = 0; ks < 4; ++ks)
            xf[ks] = __builtin_bit_cast(bf16x8, xfrag[((s * 4 + ks) << 6) + lxor]);

        f32x4 acc[4];
        #pragma unroll
        for (int c = 0; c < 4; ++c) acc[c] = (f32x4){0.f, 0.f, 0.f, 0.f};
        #pragma unroll
        for (int ks = 0; ks < 4; ++ks)
            #pragma unroll
            for (int c = 0; c < 4; ++c)
                acc[c] = __builtin_amdgcn_mfma_f32_16x16x32_bf16(
                    wf[c][ks], xf[ks], acc[c], 0, 0, 0);

        // lane holds node = s*16+lr, jj = w*64 + c*16 + lg*4 + r
        unsigned char* p = obuf + (s * 16 + lr) * OSTRIDE + w * 128 + lg * 8;
        #pragma unroll
        for (int c = 0; c < 4; ++c) {
            uint2 o;
            o.x = packbf(acc[c][0], acc[c][1]);
            o.y = packbf(acc[c][2], acc[c][3]);
            *reinterpret_cast<uint2*>(p + c * 32) = o;
        }
    }
    __syncthreads();

    // ---- Phase 3: coalesced dump (full 64B-per-row lines)
    {
        const int drow = t >> 2;
        const int dcol = (t & 3) * 16;
        const int node = base + drow;
        if (node < N) {
            const unsigned char* sp = obuf + drow * OSTRIDE + dcol;
            unsigned char* gp = reinterpret_cast<unsigned char*>(T) +
                                (size_t)node * (NT * 2) + dcol;
            #pragma unroll
            for (int i = 0; i < 8; ++i)
                *reinterpret_cast<uint4*>(gp + i * 64) =
                    *reinterpret_cast<const uint4*>(sp + i * 64);
        }
    }
}

// ---------------------------------------------------------------------------
// Edge kernel: 8 lanes/edge (R3 dot structure, measured 82us) + fast tail:
// logit-domain clamp replaces sigmoid->clip->logit; native v_log/v_exp/v_rcp.
// ---------------------------------------------------------------------------
__device__ __forceinline__ float acc_pair(uint32_t wa, uint32_t wb,
                                          float blo, float bhi,
                                          float w2lo, float w2hi, float p) {
    const float alo = __uint_as_float(wa << 16);
    const float ahi = __uint_as_float(wa & 0xffff0000u);
    const float clo = __uint_as_float(wb << 16);
    const float chi = __uint_as_float(wb & 0xffff0000u);
    const float h0 = fmaxf(alo + clo + blo, 0.f);
    const float h1 = fmaxf(ahi + chi + bhi, 0.f);
    p = fmaf(h0, w2lo, p);
    p = fmaf(h1, w2hi, p);
    return p;
}

__device__ __forceinline__ float fast_sigmoid(float xv) {
    // 1/(1+exp(-x)) = rcp(1 + exp2(-log2e * x)); saturates correctly at +-inf
    const float e = __builtin_amdgcn_exp2f(xv * -1.44269504f);
    return __builtin_amdgcn_rcpf(1.f + e);
}

__global__ __launch_bounds__(256) void edge_kernel(
    const unsigned short* __restrict__ T,
    const int* __restrict__ src, const int* __restrict__ dst,
    const float* __restrict__ b1, const float* __restrict__ W2,
    const float* __restrict__ b2,
    const float* __restrict__ u_gate, const float* __restrict__ u_bern,
    float* __restrict__ out, int E)
{
    const int gid = blockIdx.x * blockDim.x + threadIdx.x;
    const int e = gid >> 3;
    if (e >= E) return;
    const int sub = threadIdx.x & 7;

    const int s = src[e];
    const int d = dst[e];

    const uint4* Ap = reinterpret_cast<const uint4*>(T + (size_t)s * NT + sub * 16);
    const uint4* Bp = reinterpret_cast<const uint4*>(T + (size_t)d * NT + 128 + sub * 16);
    const float4* Bv = reinterpret_cast<const float4*>(b1 + sub * 16);
    const float4* Wv = reinterpret_cast<const float4*>(W2 + sub * 16);

    const uint4 a0 = Ap[0], a1 = Ap[1];
    const uint4 c0 = Bp[0], c1 = Bp[1];
    const float4 bb0 = Bv[0], bb1 = Bv[1], bb2 = Bv[2], bb3 = Bv[3];
    const float4 w0 = Wv[0], w1 = Wv[1], w2 = Wv[2], w3 = Wv[3];

    float p = 0.f;
    p = acc_pair(a0.x, c0.x, bb0.x, bb0.y, w0.x, w0.y, p);
    p = acc_pair(a0.y, c0.y, bb0.z, bb0.w, w0.z, w0.w, p);
    p = acc_pair(a0.z, c0.z, bb1.x, bb1.y, w1.x, w1.y, p);
    p = acc_pair(a0.w, c0.w, bb1.z, bb1.w, w1.z, w1.w, p);
    p = acc_pair(a1.x, c1.x, bb2.x, bb2.y, w2.x, w2.y, p);
    p = acc_pair(a1.y, c1.y, bb2.z, bb2.w, w2.z, w2.w, p);
    p = acc_pair(a1.z, c1.z, bb3.x, bb3.y, w3.x, w3.y, p);
    p = acc_pair(a1.w, c1.w, bb3.z, bb3.w, w3.z, w3.w, p);

    p += __shfl_xor(p, 1, 64);
    p += __shfl_xor(p, 2, 64);
    p += __shfl_xor(p, 4, 64);

    if (sub == 0) {
        const float logit = p + b2[0];

        // gumbel-sigmoid gate, logit domain:
        // g = ln(eps) - ln(1-eps) + logit
        const float ug  = u_gate[e];
        const float eps = fmaf(-0.9998f, ug, 0.9999f);  // in (1e-4, 0.9999]
        const float g = (__builtin_amdgcn_logf(eps) -
                         __builtin_amdgcn_logf(1.f - eps)) * 0.69314718f + logit;

        // logit(clip(sigmoid(g), .01, .99)) == clamp(g, +-ln(99))
        const float bl = fminf(fmaxf(g, -4.59511985f), 4.59511985f);

        // RelaxedBernoulli(temp=0.9).rsample; log1p(-u) == log(1-u) exactly
        // for u in [0.5,1) (Sterbenz), no cancellation below.
        const float ub  = fminf(fmaxf(u_bern[e], 1e-7f), 1.f - 1e-7f);
        const float lu  = (__builtin_amdgcn_logf(ub) -
                           __builtin_amdgcn_logf(1.f - ub)) * 0.69314718f;
        const float arg = (bl + lu) * (1.0f / 0.9f);
        out[e] = fast_sigmoid(arg);   // mask=(w>0) is identity for sigmoid
    }
}

extern "C" void kernel_launch(void* const* d_in, const int* in_sizes, int n_in,
                              void* d_out, int out_size, void* d_ws, size_t ws_size,
                              hipStream_t stream)
{
    const float* node_emb = (const float*)d_in[0];
    const int*   src      = (const int*)d_in[1];
    const int*   dst      = (const int*)d_in[2];
    const float* W1       = (const float*)d_in[3];
    const float* b1       = (const float*)d_in[4];
    const float* W2       = (const float*)d_in[5];
    const float* b2       = (const float*)d_in[6];
    const float* u_gate   = (const float*)d_in[7];
    const float* u_bern   = (const float*)d_in[8];
    float* out = (float*)d_out;

    const int N = in_sizes[0] / D;
    const int E = in_sizes[1];

    unsigned short* Wp = (unsigned short*)d_ws;            // 64 KB packed W1 frags
    unsigned short* T  = Wp + 32768;                       // [N][256] bf16

    pack_w1<<<16, 256, 0, stream>>>(W1, Wp);

    const int nMacro = (N + 63) / 64;
    node_mlp_mfma<<<nMacro, 256, 0, stream>>>(node_emb, Wp, T, N);

    const long long dotThreads = (long long)E * 8;
    const int blocksE = (int)((dotThreads + 255) / 256);
    edge_kernel<<<blocksE, 256, 0, stream>>>(T, src, dst, b1, W2, b2,
                                             u_gate, u_bern, out, E);
}

// Round 8
// 170.574 us; speedup vs baseline: 2.2437x; 1.0237x over previous
//
#include <hip/hip_runtime.h>
#include <hip/hip_bf16.h>
#include <cstdint>

#define D  128        // feature dim / MLP hidden dim
#define NT 256        // combined table row: cols 0-127 = A-part, 128-255 = B-part
#define OSTRIDE 544   // output transpose-tile row stride in bytes (512 + 32 pad)

typedef __attribute__((ext_vector_type(8))) short bf16x8;
typedef __attribute__((ext_vector_type(4))) float f32x4;

__device__ __forceinline__ unsigned int packbf(float lo, float hi) {
    const unsigned int ulo = __float_as_uint(lo) + 0x8000u;
    const unsigned int uhi = __float_as_uint(hi) + 0x8000u;
    return __builtin_amdgcn_perm(uhi, ulo, 0x07060302);  // hi16(uhi)<<16 | hi16(ulo)
}

// ---------------------------------------------------------------------------
// Pack W1cat into bf16 MFMA-fragment-linear layout (verified R3-R6).
// frag (cg,ks), lane l at uint4 index (cg*4+ks)*64 + l; elem i =
// W1[(half*128 + ks*32 + lg*8 + i)*128 + (cg&7)*16 + lr], half = cg>>3.
// ---------------------------------------------------------------------------
__global__ __launch_bounds__(256) void pack_w1(
    const float* __restrict__ W1, unsigned short* __restrict__ Wp)
{
    const int t = blockIdx.x * 256 + threadIdx.x;   // 0..4095
    if (t >= 4096) return;
    const int lane = t & 63;
    const int fc = t >> 6;
    const int cg = fc >> 2, ks = fc & 3;
    const int lr = lane & 15, lg = lane >> 4;
    const int half = cg >> 3;
    const int col = (cg & 7) * 16 + lr;
    const int krow = half * 128 + ks * 32 + lg * 8;
    const float* wp = W1 + (size_t)krow * D + col;
    uint4 u;
    u.x = packbf(wp[0 * D], wp[1 * D]);
    u.y = packbf(wp[2 * D], wp[3 * D]);
    u.z = packbf(wp[4 * D], wp[5 * D]);
    u.w = packbf(wp[6 * D], wp[7 * D]);
    reinterpret_cast<uint4*>(Wp)[t] = u;
}

// ---------------------------------------------------------------------------
// Node projection. Block handles ~2 macro-chunks of 64 nodes (grid-strided);
// W frags loaded once per block. Per chunk: pack prefetched x regs -> LDS
// frags (XOR-swizzled), B1, MFMA -> obuf transpose tile, B2, issue next
// chunk's x loads (hidden under dump), coalesced dump. 2 barriers/chunk.
// ---------------------------------------------------------------------------
__global__ __launch_bounds__(256, 3) void node_mlp_mfma(
    const float* __restrict__ x, const unsigned short* __restrict__ Wp,
    unsigned short* __restrict__ T, int N, int nMacro)
{
    __shared__ unsigned char obuf[64 * OSTRIDE];   // 34816 B
    __shared__ uint4 xfrag[1024];                  // 16384 B

    const int t = threadIdx.x;
    const int lane = t & 63;
    const int w = t >> 6;               // wave: owns jj [64w, 64w+64)
    const int lr = lane & 15;
    const int lg = lane >> 4;

    // ---- W fragments (16 per wave = 64 VGPR), once per block
    bf16x8 wf[4][4];
    {
        const uint4* wsrc = reinterpret_cast<const uint4*>(Wp);
        #pragma unroll
        for (int c = 0; c < 4; ++c)
            #pragma unroll
            for (int ks = 0; ks < 4; ++ks)
                wf[c][ks] = __builtin_bit_cast(bf16x8,
                    wsrc[(((w * 4 + c) * 4 + ks) << 6) + lane]);
    }

    int m = blockIdx.x;
    if (m >= nMacro) return;

    // ---- prologue: load x regs for first chunk (coalesced: 4 rows/wave-iter)
    float4 xr[4][2];
    #pragma unroll
    for (int i = 0; i < 4; ++i) {
        const int mm = t + 256 * i;
        int row = m * 64 + (mm >> 4); if (row > N - 1) row = N - 1;
        const float4* px = reinterpret_cast<const float4*>(x + (size_t)row * D + (mm & 15) * 8);
        xr[i][0] = px[0]; xr[i][1] = px[1];
    }

    const int lxor = lane ^ (((lane >> 4) & 3) << 2);

    for (;;) {
        const int base = m * 64;

        // ---- pack prefetched regs -> xfrag (safe: prev phase2 ended at B2)
        #pragma unroll
        for (int i = 0; i < 4; ++i) {
            const int mm = t + 256 * i;
            const int r = mm >> 4, c8 = mm & 15;
            uint4 u;
            u.x = packbf(xr[i][0].x, xr[i][0].y); u.y = packbf(xr[i][0].z, xr[i][0].w);
            u.z = packbf(xr[i][1].x, xr[i][1].y); u.w = packbf(xr[i][1].z, xr[i][1].w);
            const int s = r >> 4, lr2 = r & 15, ks = c8 >> 2, lg2 = c8 & 3;
            int idx = ((s * 4 + ks) << 6) + (lg2 << 4) + lr2;
            idx ^= ((idx >> 4) & 3) << 2;       // XOR swizzle (bijective)
            xfrag[idx] = u;
        }
        __syncthreads();   // B1: xfrag ready; prev phase3 obuf reads also done

        // ---- MFMA phase
        #pragma unroll
        for (int s = 0; s < 4; ++s) {
            bf16x8 xf[4];
            #pragma unroll
            for (int ks = 0; ks < 4; ++ks)
                xf[ks] = __builtin_bit_cast(bf16x8, xfrag[((s * 4 + ks) << 6) + lxor]);

            f32x4 acc[4];
            #pragma unroll
            for (int c = 0; c < 4; ++c) acc[c] = (f32x4){0.f, 0.f, 0.f, 0.f};
            #pragma unroll
            for (int ks = 0; ks < 4; ++ks)
                #pragma unroll
                for (int c = 0; c < 4; ++c)
                    acc[c] = __builtin_amdgcn_mfma_f32_16x16x32_bf16(
                        wf[c][ks], xf[ks], acc[c], 0, 0, 0);

            // lane holds node = s*16+lr, jj = w*64 + c*16 + lg*4 + r
            unsigned char* p = obuf + (s * 16 + lr) * OSTRIDE + w * 128 + lg * 8;
            #pragma unroll
            for (int c = 0; c < 4; ++c) {
                uint2 o;
                o.x = packbf(acc[c][0], acc[c][1]);
                o.y = packbf(acc[c][2], acc[c][3]);
                *reinterpret_cast<uint2*>(p + c * 32) = o;
            }
        }
        __syncthreads();   // B2: obuf ready; xfrag free to overwrite next iter

        // ---- issue next chunk's x loads (latency hidden under the dump)
        const int mn = m + gridDim.x;
        const bool more = (mn < nMacro);
        if (more) {
            #pragma unroll
            for (int i = 0; i < 4; ++i) {
                const int mm = t + 256 * i;
                int row = mn * 64 + (mm >> 4); if (row > N - 1) row = N - 1;
                const float4* px = reinterpret_cast<const float4*>(x + (size_t)row * D + (mm & 15) * 8);
                xr[i][0] = px[0]; xr[i][1] = px[1];
            }
        }

        // ---- coalesced dump (full 64B-per-row lines)
        {
            const int drow = t >> 2;
            const int dcol = (t & 3) * 16;
            const int node = base + drow;
            if (node < N) {
                const unsigned char* sp = obuf + drow * OSTRIDE + dcol;
                unsigned char* gp = reinterpret_cast<unsigned char*>(T) +
                                    (size_t)node * (NT * 2) + dcol;
                #pragma unroll
                for (int i = 0; i < 8; ++i)
                    *reinterpret_cast<uint4*>(gp + i * 64) =
                        *reinterpret_cast<const uint4*>(sp + i * 64);
            }
        }

        if (!more) break;
        m = mn;
    }
}

// ---------------------------------------------------------------------------
// Edge kernel: 8 lanes per PAIR of edges (2x memory-level parallelism).
// Fast logit-domain tail (verified R6) on lane sub==0, float2 stores.
// ---------------------------------------------------------------------------
__device__ __forceinline__ float acc_pair(uint32_t wa, uint32_t wb,
                                          float blo, float bhi,
                                          float w2lo, float w2hi, float p) {
    const float alo = __uint_as_float(wa << 16);
    const float ahi = __uint_as_float(wa & 0xffff0000u);
    const float clo = __uint_as_float(wb << 16);
    const float chi = __uint_as_float(wb & 0xffff0000u);
    const float h0 = fmaxf(alo + clo + blo, 0.f);
    const float h1 = fmaxf(ahi + chi + bhi, 0.f);
    p = fmaf(h0, w2lo, p);
    p = fmaf(h1, w2hi, p);
    return p;
}

__device__ __forceinline__ float fast_sigmoid(float xv) {
    const float e = __builtin_amdgcn_exp2f(xv * -1.44269504f);
    return __builtin_amdgcn_rcpf(1.f + e);
}

__device__ __forceinline__ float tail_math(float logit, float ug, float ubr) {
    // gumbel-sigmoid gate, logit domain
    const float eps = fmaf(-0.9998f, ug, 0.9999f);  // in (1e-4, 0.9999]
    const float g = (__builtin_amdgcn_logf(eps) -
                     __builtin_amdgcn_logf(1.f - eps)) * 0.69314718f + logit;
    // logit(clip(sigmoid(g), .01, .99)) == clamp(g, +-ln(99))
    const float bl = fminf(fmaxf(g, -4.59511985f), 4.59511985f);
    // RelaxedBernoulli(temp=0.9).rsample
    const float ub = fminf(fmaxf(ubr, 1e-7f), 1.f - 1e-7f);
    const float lu = (__builtin_amdgcn_logf(ub) -
                      __builtin_amdgcn_logf(1.f - ub)) * 0.69314718f;
    return fast_sigmoid((bl + lu) * (1.0f / 0.9f));  // mask=(w>0) identity
}

__global__ __launch_bounds__(256) void edge_kernel(
    const unsigned short* __restrict__ T,
    const int* __restrict__ src, const int* __restrict__ dst,
    const float* __restrict__ b1, const float* __restrict__ W2,
    const float* __restrict__ b2,
    const float* __restrict__ u_gate, const float* __restrict__ u_bern,
    float* __restrict__ out, int E)
{
    const int gid = blockIdx.x * blockDim.x + threadIdx.x;
    const int p = gid >> 3;                 // pair index
    const int P = E >> 1;
    if (p >= P) return;
    const int sub = threadIdx.x & 7;

    const int2 ss = *reinterpret_cast<const int2*>(src + 2 * p);
    const int2 dd = *reinterpret_cast<const int2*>(dst + 2 * p);

    const uint4* Ap0 = reinterpret_cast<const uint4*>(T + (size_t)ss.x * NT + sub * 16);
    const uint4* Cp0 = reinterpret_cast<const uint4*>(T + (size_t)dd.x * NT + 128 + sub * 16);
    const uint4* Ap1 = reinterpret_cast<const uint4*>(T + (size_t)ss.y * NT + sub * 16);
    const uint4* Cp1 = reinterpret_cast<const uint4*>(T + (size_t)dd.y * NT + 128 + sub * 16);

    // 8 independent gathers in flight
    const uint4 a00 = Ap0[0], a01 = Ap0[1];
    const uint4 c00 = Cp0[0], c01 = Cp0[1];
    const uint4 a10 = Ap1[0], a11 = Ap1[1];
    const uint4 c10 = Cp1[0], c11 = Cp1[1];

    const float4* Bv = reinterpret_cast<const float4*>(b1 + sub * 16);
    const float4* Wv = reinterpret_cast<const float4*>(W2 + sub * 16);
    const float4 bb0 = Bv[0], bb1 = Bv[1], bb2 = Bv[2], bb3 = Bv[3];
    const float4 w0 = Wv[0], w1 = Wv[1], w2 = Wv[2], w3 = Wv[3];

    float p0 = 0.f, p1 = 0.f;
    p0 = acc_pair(a00.x, c00.x, bb0.x, bb0.y, w0.x, w0.y, p0);
    p1 = acc_pair(a10.x, c10.x, bb0.x, bb0.y, w0.x, w0.y, p1);
    p0 = acc_pair(a00.y, c00.y, bb0.z, bb0.w, w0.z, w0.w, p0);
    p1 = acc_pair(a10.y, c10.y, bb0.z, bb0.w, w0.z, w0.w, p1);
    p0 = acc_pair(a00.z, c00.z, bb1.x, bb1.y, w1.x, w1.y, p0);
    p1 = acc_pair(a10.z, c10.z, bb1.x, bb1.y, w1.x, w1.y, p1);
    p0 = acc_pair(a00.w, c00.w, bb1.z, bb1.w, w1.z, w1.w, p0);
    p1 = acc_pair(a10.w, c10.w, bb1.z, bb1.w, w1.z, w1.w, p1);
    p0 = acc_pair(a01.x, c01.x, bb2.x, bb2.y, w2.x, w2.y, p0);
    p1 = acc_pair(a11.x, c11.x, bb2.x, bb2.y, w2.x, w2.y, p1);
    p0 = acc_pair(a01.y, c01.y, bb2.z, bb2.w, w2.z, w2.w, p0);
    p1 = acc_pair(a11.y, c11.y, bb2.z, bb2.w, w2.z, w2.w, p1);
    p0 = acc_pair(a01.z, c01.z, bb3.x, bb3.y, w3.x, w3.y, p0);
    p1 = acc_pair(a11.z, c11.z, bb3.x, bb3.y, w3.x, w3.y, p1);
    p0 = acc_pair(a01.w, c01.w, bb3.z, bb3.w, w3.z, w3.w, p0);
    p1 = acc_pair(a11.w, c11.w, bb3.z, bb3.w, w3.z, w3.w, p1);

    p0 += __shfl_xor(p0, 1, 64);  p1 += __shfl_xor(p1, 1, 64);
    p0 += __shfl_xor(p0, 2, 64);  p1 += __shfl_xor(p1, 2, 64);
    p0 += __shfl_xor(p0, 4, 64);  p1 += __shfl_xor(p1, 4, 64);

    if (sub == 0) {
        const float b2v = b2[0];
        const float2 ug = *reinterpret_cast<const float2*>(u_gate + 2 * p);
        const float2 ub = *reinterpret_cast<const float2*>(u_bern + 2 * p);
        float2 o;
        o.x = tail_math(p0 + b2v, ug.x, ub.x);
        o.y = tail_math(p1 + b2v, ug.y, ub.y);
        *reinterpret_cast<float2*>(out + 2 * p) = o;
    }
}

extern "C" void kernel_launch(void* const* d_in, const int* in_sizes, int n_in,
                              void* d_out, int out_size, void* d_ws, size_t ws_size,
                              hipStream_t stream)
{
    const float* node_emb = (const float*)d_in[0];
    const int*   src      = (const int*)d_in[1];
    const int*   dst      = (const int*)d_in[2];
    const float* W1       = (const float*)d_in[3];
    const float* b1       = (const float*)d_in[4];
    const float* W2       = (const float*)d_in[5];
    const float* b2       = (const float*)d_in[6];
    const float* u_gate   = (const float*)d_in[7];
    const float* u_bern   = (const float*)d_in[8];
    float* out = (float*)d_out;

    const int N = in_sizes[0] / D;     // 100000
    const int E = in_sizes[1];         // 800000 (even)

    unsigned short* Wp = (unsigned short*)d_ws;            // 64 KB packed W1 frags
    unsigned short* T  = Wp + 32768;                       // [N][256] bf16

    pack_w1<<<16, 256, 0, stream>>>(W1, Wp);

    const int nMacro = (N + 63) / 64;                      // 1563
    const int gridN = (nMacro + 1) / 2;                    // 782: <=2 chunks/block
    node_mlp_mfma<<<gridN, 256, 0, stream>>>(node_emb, Wp, T, N, nMacro);

    const int P = E >> 1;
    const long long thr = (long long)P * 8;
    const int blocksE = (int)((thr + 255) / 256);
    edge_kernel<<<blocksE, 256, 0, stream>>>(T, src, dst, b1, W2, b2,
                                             u_gate, u_bern, out, E);
}